// Round 7
// baseline (61.908 us; speedup 1.0000x reference)
//
#include <hip/hip_runtime.h>

#define HW     16384
#define WDIM   128
#define CDIM   64
#define BDIM   32
#define NBF    4096     // (b,row) partial rows (unchanged layout for k3/k4)
#define NBG    1024     // fused blocks: (b, rowgroup of 4)
#define NBC    2048     // (b,c) pairs

// ws layout (bytes). Per-channel partial arrays are C-MAJOR [64][4096] so
// k3_channel reads are unit-stride coalesced.
#define OFF_WMAX  0
#define OFF_WIDX  (1u << 20)
#define OFF_WSF   (2u << 20)
#define OFF_WS0   (3u << 20)
#define OFF_WSJ   (4u << 20)
#define OFF_WSQJ  (5u << 20)
#define OFF_WA1   (6u << 20)
#define OFF_WA2   ((6u << 20) + 32768u)
#define OFF_K3    ((6u << 20) + 65536u)

// Fused single pass, software-pipelined: block = (b, 4-row group).
// Per row: tile 64ch x 128px in LDS (stride 129: all patterns <=2-way = free).
// Row r+1's global loads are issued right after row r's tile write, so the
// LDS/VALU processing phases always have the next row's 32 KB in flight.
__global__ __launch_bounds__(256, 4) void f_fused(const float* __restrict__ feat,
                                                  float* __restrict__ wmax, int* __restrict__ widx,
                                                  float* __restrict__ wsf,  float* __restrict__ ws0,
                                                  float* __restrict__ wsj,  float* __restrict__ wsqj,
                                                  double* __restrict__ wa1, double* __restrict__ wa2) {
    __shared__ float tile[CDIM * 129];      // 33024 B
    __shared__ float scratch[1792];         // union: 2a sc2[128*3] -> 2b scb[4*64*7]
    __shared__ float sred[4];               // a1,a2 wave partials

    const int t  = threadIdx.x;
    const int bq = blockIdx.x;              // b*32 + rowgroup
    const int b  = bq >> 5, rg = bq & 31;
    const int row0 = rg * 4;
    const float* srcb = feat + (size_t)b * CDIM * HW + (size_t)row0 * WDIM;

    // per-thread load geometry (same for every row): c = idx>>5, g = idx&31
    const int px = t & 127, half = t >> 7;           // phase 2a roles
    const int ch = t & 63, sub = t >> 6, p0 = sub * 32;  // phase 2b roles

    // prologue: load row 0
    float4 buf[8];
    #pragma unroll
    for (int k = 0; k < 8; ++k) {
        int idx = k * 256 + t;
        int c = idx >> 5, g = idx & 31;
        buf[k] = *(const float4*)(srcb + (size_t)c * HW + g * 4);
    }

    #pragma unroll
    for (int r = 0; r < 4; ++r) {
        const int bf = b * 128 + row0 + r;

        // ---- stage current row to LDS
        #pragma unroll
        for (int k = 0; k < 8; ++k) {
            int idx = k * 256 + t;
            int c = idx >> 5, g = idx & 31;
            float* dst = &tile[c * 129 + g * 4];
            dst[0] = buf[k].x; dst[1] = buf[k].y; dst[2] = buf[k].z; dst[3] = buf[k].w;
        }

        // ---- issue NEXT row's loads (in flight across the processing below)
        float4 nbuf[8];
        if (r < 3) {
            #pragma unroll
            for (int k = 0; k < 8; ++k) {
                int idx = k * 256 + t;
                int c = idx >> 5, g = idx & 31;
                nbuf[k] = *(const float4*)(srcb + (size_t)(r + 1) * WDIM + (size_t)c * HW + g * 4);
            }
        }
        __syncthreads();   // B1: tile ready

        // ---- Phase 2a scan: px = t&127, half scans 32 ch
        float m1 = -INFINITY, m2 = -INFINITY, s2 = 0.f;
        #pragma unroll
        for (int cc = 0; cc < 32; ++cc) {
            float x = tile[(half * 32 + cc) * 129 + px];
            if (x > m1) { m2 = m1; m1 = x; } else { m2 = fmaxf(m2, x); }
            s2 = fmaf(x, x, s2);
        }
        if (half) { scratch[px * 3] = m1; scratch[px * 3 + 1] = m2; scratch[px * 3 + 2] = s2; }
        __syncthreads();   // B2

        // ---- Phase 2b scan (all threads, from stable tile)
        float bm = -INFINITY; int bi = 0;
        float sf = 0.f, s0 = 0.f, sjl = 0.f, sql = 0.f;
        #pragma unroll
        for (int i = 0; i < 32; ++i) {
            float x = tile[ch * 129 + p0 + i];
            if (x > bm) { bm = x; bi = i; }      // ascending i: strict > keeps first
            sf += x;
            float q = x * x;
            s0 += q;
            sjl = fmaf(q, (float)i, sjl);
            sql = fmaf(q, (float)(i * i), sql);
        }

        // ---- 2a merge + shfl reduce (waves 0-1; px == t, wave-uniform branch)
        if (!half) {
            float n1 = scratch[px * 3], n2 = scratch[px * 3 + 1], s2b = scratch[px * 3 + 2];
            float mm1 = fmaxf(m1, n1);
            float mm2 = fmaxf(fminf(m1, n1), fmaxf(m2, n2));
            float S2 = s2 + s2b;
            float qq = mm1 * mm1, rr2 = S2 - qq;
            float a1 = qq * rr2 + mm2 * mm2 * qq;
            float a2 = mm1 * rr2 + mm2 * qq;
            #pragma unroll
            for (int off = 32; off > 0; off >>= 1) {
                a1 += __shfl_down(a1, off);
                a2 += __shfl_down(a2, off);
            }
            if (t == 0)  { sred[0] = a1; sred[1] = a2; }
            if (t == 64) { sred[2] = a1; sred[3] = a2; }
        }
        __syncthreads();   // B3: sc2 reads done -> scratch reusable; sred visible

        // ---- write 2b sub-partials
        {
            float sj  = fmaf((float)p0, s0, sjl);
            float sqj = fmaf((float)(p0 * p0), s0, fmaf(2.f * (float)p0, sjl, sql));
            int o = (sub * 64 + ch) * 7;
            scratch[o]     = bm;
            scratch[o + 1] = __int_as_float(p0 + bi);
            scratch[o + 2] = sf; scratch[o + 3] = s0;
            scratch[o + 4] = sj; scratch[o + 5] = sqj;
        }
        if (t == 255) {
            wa1[bf] = (double)(sred[0] + sred[2]);
            wa2[bf] = (double)(sred[1] + sred[3]);
        }
        __syncthreads();   // B4

        // ---- combine 4 subs per channel, write c-major partials
        if (t < 64) {
            float M = -INFINITY; int P = 0;
            float SF = 0.f, S0 = 0.f, SJ = 0.f, SQ = 0.f;
            #pragma unroll
            for (int s = 0; s < 4; ++s) {
                int oo = (s * 64 + t) * 7;
                float m = scratch[oo];
                if (m > M) { M = m; P = __float_as_int(scratch[oo + 1]); }
                SF += scratch[oo + 2]; S0 += scratch[oo + 3];
                SJ += scratch[oo + 4]; SQ += scratch[oo + 5];
            }
            int out = t * 4096 + bf;             // [c][4096] c-major
            wmax[out] = M; widx[out] = P;
            wsf[out] = SF; ws0[out] = S0; wsj[out] = SJ; wsqj[out] = SQ;
        }
        // (no barrier needed: next iter's tile writes are fenced by B4; the
        //  t<64 combine reads scb, whose next write is after next-iter B2)

        // rotate pipeline registers
        if (r < 3) {
            #pragma unroll
            for (int k = 0; k < 8; ++k) buf[k] = nbuf[k];
        }
    }
}

// One block per (b,c): merge 128 row partials (unit-stride coalesced).
// dis = sum_rows ((mi-row)^2 + mj^2)*s0 - 2*mj*sj + sqj.
__global__ __launch_bounds__(128) void k3_channel(const float* __restrict__ wmax, const int* __restrict__ widx,
                                                  const float* __restrict__ wsf,  const float* __restrict__ ws0,
                                                  const float* __restrict__ wsj,  const float* __restrict__ wsqj,
                                                  double* __restrict__ k3out) {
    const int bc = blockIdx.x;             // b*64 + c
    const int b = bc >> 6, c = bc & 63;
    const int t = threadIdx.x;             // row
    const int idx = c * 4096 + b * 128 + t;

    float m = wmax[idx]; int px = widx[idx];
    float sf = wsf[idx], s0 = ws0[idx], sj = wsj[idx], sqj = wsqj[idx];

    __shared__ float rm[128]; __shared__ int rr[128]; __shared__ int rp[128];
    rm[t] = m; rr[t] = t; rp[t] = px;
    __syncthreads();
    for (int off = 64; off > 0; off >>= 1) {
        if (t < off) {
            float mo = rm[t + off];
            if (mo > rm[t] || (mo == rm[t] && rr[t + off] < rr[t])) {
                rm[t] = mo; rr[t] = rr[t + off]; rp[t] = rp[t + off];
            }
        }
        __syncthreads();
    }
    const int mi = rr[0], mj = rp[0];

    double di = (double)(mi - t);
    double disc = (di * di + (double)mj * (double)mj) * (double)s0
                - 2.0 * (double)mj * (double)sj + (double)sqj;

    __shared__ double rd[128], rsf[128], rs0[128];
    rd[t] = disc; rsf[t] = (double)sf; rs0[t] = (double)s0;
    __syncthreads();
    for (int off = 64; off > 0; off >>= 1) {
        if (t < off) { rd[t] += rd[t + off]; rsf[t] += rsf[t + off]; rs0[t] += rs0[t + off]; }
        __syncthreads();
    }
    if (t == 0) {
        k3out[bc * 3]     = rsf[0];
        k3out[bc * 3 + 1] = rs0[0];
        k3out[bc * 3 + 2] = rd[0];
    }
}

__global__ __launch_bounds__(256) void k4_final(const double* __restrict__ k3out,
                                                const double* __restrict__ wa1,
                                                const double* __restrict__ wa2,
                                                float* __restrict__ out) {
    const int t = threadIdx.x;
    double sf = 0, s0 = 0, dis = 0, a1 = 0, a2 = 0;
    for (int i = t; i < NBC; i += 256) {
        sf += k3out[i * 3]; s0 += k3out[i * 3 + 1]; dis += k3out[i * 3 + 2];
    }
    for (int i = t; i < NBF; i += 256) { a1 += wa1[i]; a2 += wa2[i]; }

    __shared__ double r[5][256];
    r[0][t] = sf; r[1][t] = s0; r[2][t] = dis; r[3][t] = a1; r[4][t] = a2;
    __syncthreads();
    for (int off = 128; off > 0; off >>= 1) {
        if (t < off) {
            #pragma unroll
            for (int q = 0; q < 5; ++q) r[q][t] += r[q][t + off];
        }
        __syncthreads();
    }
    if (t == 0) {
        const double n = 33554432.0; // 32*64*128*128
        double mgr = r[0][0] / n;
        out[0] = (float)(r[2][0] / n);
        out[1] = (float)((r[3][0] - 2.0 * mgr * r[4][0] + mgr * mgr * r[1][0]) / n);
    }
}

extern "C" void kernel_launch(void* const* d_in, const int* in_sizes, int n_in,
                              void* d_out, int out_size, void* d_ws, size_t ws_size,
                              hipStream_t stream) {
    const float* feat = (const float*)d_in[0];
    float* out = (float*)d_out;
    char* ws = (char*)d_ws;

    float*  wmax = (float*)(ws + OFF_WMAX);
    int*    widx = (int*)  (ws + OFF_WIDX);
    float*  wsf  = (float*)(ws + OFF_WSF);
    float*  ws0  = (float*)(ws + OFF_WS0);
    float*  wsj  = (float*)(ws + OFF_WSJ);
    float*  wsqj = (float*)(ws + OFF_WSQJ);
    double* wa1  = (double*)(ws + OFF_WA1);
    double* wa2  = (double*)(ws + OFF_WA2);
    double* k3o  = (double*)(ws + OFF_K3);

    f_fused<<<NBG, 256, 0, stream>>>(feat, wmax, widx, wsf, ws0, wsj, wsqj, wa1, wa2);
    k3_channel<<<NBC, 128, 0, stream>>>(wmax, widx, wsf, ws0, wsj, wsqj, k3o);
    k4_final<<<1, 256, 0, stream>>>(k3o, wa1, wa2, out);
}

// Round 8
// 57.891 us; speedup vs baseline: 1.0694x; 1.0694x over previous
//
#include <hip/hip_runtime.h>

#define HW    16384
#define WDIM  128
#define CDIM  64
#define BDIM  32
#define NK2   512             // pixel-direction blocks (first in grid: 4x longer)
#define NK1   2048            // channel-direction blocks, one (b,c) each
#define NGRID (NK1 + NK2)

// ws layout (doubles):
//   [0    .. 2047]  per-(b,c) sum f
//   [2048 .. 4095]  per-(b,c) sum f^2
//   [4096 .. 6143]  per-(b,c) dis partial
//   [6144 .. 6655]  per-pixel-block A1 (512)
//   [6656 .. 7167]  per-pixel-block A2 (512)

// Heterogeneous grid: block role by blockIdx. Both roles are pure streaming
// (no LDS tile, no barriers in the hot loop) -> ~10 co-resident blocks/CU keep
// VMEM saturated continuously; VALU/DS hide underneath.
__global__ __launch_bounds__(256) void fused_streams(const float* __restrict__ feat,
                                                     double* __restrict__ ws) {
    const int t = threadIdx.x;

    if (blockIdx.x < NK2) {
        // ---- Pixel-direction role: 4 px/thread via float4, walk 64 channels.
        // Closed form per pixel: with m1,m2 = top2 over c, S2 = sum_c f^2:
        //   A1_px = m1^2*(S2-m1^2) + m2^2*m1^2 ;  A2_px = m1*(S2-m1^2) + m2*m1^2
        const int p4 = blockIdx.x * 256 + t;     // float4 idx in [0, B*HW/4)
        const int b   = p4 >> 12;                // 4096 float4 per image
        const int hw4 = p4 & 4095;
        const float4* src = (const float4*)(feat + (size_t)b * CDIM * HW) + hw4;

        float m1x=-INFINITY, m2x=-INFINITY, s2x=0.f;
        float m1y=-INFINITY, m2y=-INFINITY, s2y=0.f;
        float m1z=-INFINITY, m2z=-INFINITY, s2z=0.f;
        float m1w=-INFINITY, m2w=-INFINITY, s2w=0.f;

        #pragma unroll
        for (int c = 0; c < CDIM; ++c) {
            float4 v = src[c * (HW / 4)];
            if (v.x > m1x) { m2x = m1x; m1x = v.x; } else { m2x = fmaxf(m2x, v.x); }
            if (v.y > m1y) { m2y = m1y; m1y = v.y; } else { m2y = fmaxf(m2y, v.y); }
            if (v.z > m1z) { m2z = m1z; m1z = v.z; } else { m2z = fmaxf(m2z, v.z); }
            if (v.w > m1w) { m2w = m1w; m1w = v.w; } else { m2w = fmaxf(m2w, v.w); }
            s2x = fmaf(v.x, v.x, s2x);
            s2y = fmaf(v.y, v.y, s2y);
            s2z = fmaf(v.z, v.z, s2z);
            s2w = fmaf(v.w, v.w, s2w);
        }

        float a1, a2;
        {
            float qx = m1x*m1x, qy = m1y*m1y, qz = m1z*m1z, qw = m1w*m1w;
            float rx = s2x - qx, ry = s2y - qy, rz = s2z - qz, rw = s2w - qw;
            a1 = qx*rx + m2x*m2x*qx
               + qy*ry + m2y*m2y*qy
               + qz*rz + m2z*m2z*qz
               + qw*rw + m2w*m2w*qw;
            a2 = m1x*rx + m2x*qx
               + m1y*ry + m2y*qy
               + m1z*rz + m2z*qz
               + m1w*rw + m2w*qw;
        }

        __shared__ float r1[256], r2[256];
        r1[t] = a1; r2[t] = a2;
        __syncthreads();
        for (int off = 128; off > 0; off >>= 1) {
            if (t < off) { r1[t] += r1[t + off]; r2[t] += r2[t + off]; }
            __syncthreads();
        }
        if (t == 0) {
            ws[6144 + blockIdx.x] = (double)r1[0];
            ws[6656 + blockIdx.x] = (double)r2[0];
        }
    } else {
        // ---- Channel-direction role: one (b,c), 16 float4/thread batched.
        // dis = (mi^2+mj^2)*T0 + TQ - 2*mi*TI - 2*mj*TJ (argmax-independent sums)
        const int cb = blockIdx.x - NK2;
        const size_t base = (size_t)cb * HW;
        const float4* f4 = (const float4*)(feat + base);

        float4 buf[16];
        #pragma unroll
        for (int k = 0; k < 16; ++k) buf[k] = f4[t + k * 256];

        float best = -INFINITY; int bidx = 0;
        float sf = 0.f, s0 = 0.f, si = 0.f, sj = 0.f, sq = 0.f;
        #pragma unroll
        for (int k = 0; k < 16; ++k) {
            int p = t + k * 256;
            int e = p * 4;
            int i  = e >> 7;
            int jb = e & 127;
            float x0 = buf[k].x, x1 = buf[k].y, x2 = buf[k].z, x3 = buf[k].w;
            if (x0 > best) { best = x0; bidx = e;     }
            if (x1 > best) { best = x1; bidx = e + 1; }
            if (x2 > best) { best = x2; bidx = e + 2; }
            if (x3 > best) { best = x3; bidx = e + 3; }
            float q0 = x0*x0, q1 = x1*x1, q2 = x2*x2, q3 = x3*x3;
            float qs = q0 + q1 + q2 + q3;
            sf += x0 + x1 + x2 + x3;
            s0 += qs;
            si += qs * (float)i;
            sj += q0*(float)jb + q1*(float)(jb+1) + q2*(float)(jb+2) + q3*(float)(jb+3);
            float ii = (float)(i * i);
            sq += q0*(ii + (float)( jb   * jb   ))
                + q1*(ii + (float)((jb+1)*(jb+1)))
                + q2*(ii + (float)((jb+2)*(jb+2)))
                + q3*(ii + (float)((jb+3)*(jb+3)));
        }

        __shared__ float smax[256]; __shared__ int sidx[256];
        __shared__ float rf[256], r0[256], ri[256], rj[256], rq[256];
        smax[t] = best; sidx[t] = bidx;
        rf[t] = sf; r0[t] = s0; ri[t] = si; rj[t] = sj; rq[t] = sq;
        __syncthreads();

        for (int off = 128; off > 0; off >>= 1) {
            if (t < off) {
                float vo = smax[t + off]; int io = sidx[t + off];
                if (vo > smax[t] || (vo == smax[t] && io < sidx[t])) { smax[t] = vo; sidx[t] = io; }
                rf[t] += rf[t + off]; r0[t] += r0[t + off];
                ri[t] += ri[t + off]; rj[t] += rj[t + off]; rq[t] += rq[t + off];
            }
            __syncthreads();
        }

        if (t == 0) {
            int mi = sidx[0] >> 7, mj = sidx[0] & 127;
            double T0 = r0[0], TI = ri[0], TJ = rj[0], TQ = rq[0];
            double dis = (double)(mi*mi + mj*mj) * T0 + TQ - 2.0*mi*TI - 2.0*mj*TJ;
            ws[cb]        = (double)rf[0];
            ws[2048 + cb] = T0;
            ws[4096 + cb] = dis;
        }
    }
}

__global__ __launch_bounds__(256) void k4_final(const double* __restrict__ ws,
                                                float* __restrict__ out) {
    const int t = threadIdx.x;
    double sf = 0, s0 = 0, dis = 0, a1 = 0, a2 = 0;
    for (int i = t; i < NK1; i += 256) {
        sf  += ws[i];
        s0  += ws[2048 + i];
        dis += ws[4096 + i];
    }
    for (int i = t; i < NK2; i += 256) {
        a1 += ws[6144 + i];
        a2 += ws[6656 + i];
    }
    __shared__ double r[5][256];
    r[0][t] = sf; r[1][t] = s0; r[2][t] = dis; r[3][t] = a1; r[4][t] = a2;
    __syncthreads();
    for (int off = 128; off > 0; off >>= 1) {
        if (t < off) {
            #pragma unroll
            for (int q = 0; q < 5; ++q) r[q][t] += r[q][t + off];
        }
        __syncthreads();
    }
    if (t == 0) {
        const double n = 33554432.0; // 32*64*128*128
        double mgr = r[0][0] / n;
        out[0] = (float)(r[2][0] / n);
        out[1] = (float)((r[3][0] - 2.0 * mgr * r[4][0] + mgr * mgr * r[1][0]) / n);
    }
}

extern "C" void kernel_launch(void* const* d_in, const int* in_sizes, int n_in,
                              void* d_out, int out_size, void* d_ws, size_t ws_size,
                              hipStream_t stream) {
    const float* feat = (const float*)d_in[0];
    float* out = (float*)d_out;
    double* ws = (double*)d_ws;

    fused_streams<<<NGRID, 256, 0, stream>>>(feat, ws);
    k4_final<<<1, 256, 0, stream>>>(ws, out);
}